// Round 17
// baseline (337.074 us; speedup 1.0000x reference)
//
#include <hip/hip_runtime.h>
#include <math.h>

typedef __attribute__((ext_vector_type(8))) short s16x8;
typedef __attribute__((ext_vector_type(4))) short s16x4;
typedef __attribute__((ext_vector_type(4))) float f32x4;

typedef unsigned int u32;
typedef __attribute__((address_space(3))) u32* lds_u32p;
typedef const __attribute__((address_space(1))) u32* glb_u32p;

namespace {

constexpr int B  = 8;
constexpr int C  = 192;
constexpr int H  = 96;
constexpr int W  = 96;
constexpr int FK = 9;
constexpr int HP = 98;    // padded
constexpr int L  = 1024;  // 32x32 patch grid per phase
constexpr int WCHUNK = FK * 12 * 6;          // 648 packed 1KB chunks per tensor
constexpr int WELEM  = WCHUNK * 512;         // 331776 bf16 elements
constexpr size_t XPAD_ELEMS = (size_t)B * HP * HP * 192;

__device__ inline unsigned short f2b(float f) {
    unsigned int x = __float_as_uint(f);
    x += 0x7fffu + ((x >> 16) & 1u);
    return (unsigned short)(x >> 16);
}

// ---------------------------------------------------------------------------
// MERGED prep: [0,4608) prep_x (x->xpadT bf16 channel-last, both tensors),
// [4608,7200) prep_w (fragment-linear weight pack, both tensors),
// [7200,7782) border_zero (zero pad borders of both xpad tensors).
// ---------------------------------------------------------------------------
__global__ __launch_bounds__(256) void prep_all(const float* __restrict__ x1,
                                                const float* __restrict__ x2,
                                                const float* __restrict__ kw,
                                                const float* __restrict__ qw,
                                                unsigned short* __restrict__ xpadT,
                                                unsigned short* __restrict__ kwA,
                                                unsigned short* __restrict__ qwA) {
    __shared__ float xs[192][33];
    const int gid = blockIdx.x;
    const int tid = threadIdx.x;

    if (gid < 4608) {
        const int bx = gid % 3, by = (gid / 3) % 96, bz = gid / 288;
        const int x0 = bx * 32, y = by;
        const int b = bz & 7, t = bz >> 3;
        const float* x = t ? x2 : x1;
        unsigned short* dst = xpadT + (size_t)t * XPAD_ELEMS;
        for (int e = tid; e < 192 * 32; e += 256) {
            const int ci = e >> 5, xx = e & 31;
            xs[ci][xx] = x[(((size_t)b * C + ci) * H + y) * W + x0 + xx];
        }
        __syncthreads();
        for (int e = tid; e < 32 * 192; e += 256) {
            const int pos = e / 192, ci = e - pos * 192;
            dst[(((size_t)(b * HP + y + 1)) * HP + x0 + pos + 1) * 192 + ci] =
                f2b(xs[ci][pos]);
        }
    } else if (gid < 7200) {
        int idx = (gid - 4608) * 256 + tid;
        const float* src = kw;
        unsigned short* dst = kwA;
        if (idx >= WELEM) { idx -= WELEM; src = qw; dst = qwA; }
        const int chunk = idx >> 9, within = idx & 511;
        const int lane = within >> 3, t = within & 7;
        const int kg = lane >> 4, r15 = lane & 15;
        const int cc = chunk % 6, c2 = chunk / 6;
        const int cot = c2 % 12, p = c2 / 12;
        const int co = cot * 16 + r15;
        const int ci = cc * 32 + kg * 8 + t;
        dst[idx] = f2b(src[((size_t)co * C + ci) * FK + p]);
    } else {
        const int c   = (gid - 7200) * 256 + tid;
        const int c16 = c % 24;
        const int p_  = c / 24;
        const int pos = p_ % 388;
        const int bt  = p_ / 388;      // 0..15 spans xpad1 then xpad2
        int yy, xx;
        if (pos < 98)       { yy = 0;          xx = pos; }
        else if (pos < 196) { yy = 97;         xx = pos - 98; }
        else if (pos < 292) { yy = pos - 195;  xx = 0; }
        else                { yy = pos - 291;  xx = 97; }
        const size_t off = (((size_t)bt * HP + yy) * HP + xx) * 192 + c16 * 8;
        *(s16x8*)(xpadT + off) = (s16x8){0, 0, 0, 0, 0, 0, 0, 0};
    }
}

// ---------------------------------------------------------------------------
// FRONT conv = R14 optimum + REGISTER-PREFETCHED af (double-buffered weight
// fragments): cur/nxt selected by compile-time cc&1; next iteration's 9 af
// loads issued BEFORE this iteration's MFMAs, incl. across the dy barrier
// (af loads are global, independent of the LDS row buffer). VGPR budget:
// afA+afB 72 + acc 36 + addr/bv ~40 = ~150 < 170 cap at (256,3).
// Spill signature = WRITE_SIZE >> 69MB -> revert to R14.
// XCD-affinity map (FETCH 101->41MB measured), 2x19.2KB LDS dbuf,
// stage(dy+1) at cc==5 pinned by sched_barriers.
// ---------------------------------------------------------------------------
__global__ __launch_bounds__(256, 3)
void conv_front(const unsigned short* __restrict__ xpadA,
                const unsigned short* __restrict__ xpadB,
                const unsigned short* __restrict__ wA,
                const unsigned short* __restrict__ wB,
                void* __restrict__ youtA,
                void* __restrict__ youtB) {
    __shared__ __align__(16) char smem[2][19200];
    const int tid  = threadIdx.x;
    const int id   = blockIdx.x;            // 0..3071
    const int xcd  = id & 7;
    const int j    = id >> 3;               // 0..383
    const int pair = j / 192;               // 0..1
    const int k    = j - pair * 192;
    const int sx   = k & 1;
    const int y    = k >> 1;                // 0..95
    const int bt   = xcd * 2 + pair;        // 0..15
    const int b    = bt & 7;
    const int t    = bt >> 3;
    const unsigned short* xpadT = t ? xpadB : xpadA;
    const unsigned short* wp    = t ? wB : wA;
    void* yout = t ? youtB : youtA;
    const int lane = tid & 63, wc = tid >> 6;
    const int ln15 = lane & 15, kg = lane >> 4;

    // staging: 50 pos x 24 chunks(16B) = 1200 chunks; 4 rounds + 176 tail
    int gfull[4];
#pragma unroll
    for (int it = 0; it < 4; ++it) {
        const int m = it * 256 + tid;
        const int q = m / 24, c16 = m - q * 24;
        gfull[it] = (sx * 48 + q) * 384 + ((c16 * 16) ^ ((q & 7) << 4));
    }
    int gtail = 0;
    if (tid < 176) {
        const int m = 1024 + tid;
        const int q = m / 24, c16 = m - q * 24;
        gtail = (sx * 48 + q) * 384 + ((c16 * 16) ^ ((q & 7) << 4));
    }

    auto stage = [&](char* lb, int prow) {
        const char* rowbase = (const char*)(xpadT + ((size_t)(b * HP + prow)) * HP * 192);
#pragma unroll
        for (int it = 0; it < 4; ++it)
            __builtin_amdgcn_global_load_lds(
                (glb_u32p)(const void*)(rowbase + gfull[it]),
                (lds_u32p)(void*)(lb + it * 4096 + wc * 1024), 16, 0, 0);
        if (tid < 176)
            __builtin_amdgcn_global_load_lds(
                (glb_u32p)(const void*)(rowbase + gtail),
                (lds_u32p)(void*)(lb + 16384 + wc * 1024), 16, 0, 0);
    };

    auto loadAF = [&](s16x8 (&dst)[3][3], int dyy, int ccc) {
#pragma unroll
        for (int dx = 0; dx < 3; ++dx)
#pragma unroll
            for (int i = 0; i < 3; ++i) {
                const int chunkid = ((3 * dyy + dx) * 12 + wc * 3 + i) * 6 + ccc;
                dst[dx][i] = *(const s16x8*)(wp + (size_t)chunkid * 512 + lane * 8);
            }
    };

    f32x4 acc[3][3];
#pragma unroll
    for (int i = 0; i < 3; ++i)
#pragma unroll
        for (int j2 = 0; j2 < 3; ++j2)
            acc[i][j2] = (f32x4){0.f, 0.f, 0.f, 0.f};

    s16x8 afA[3][3], afB[3][3];
    stage(smem[0], y);
    loadAF(afA, 0, 0);          // prefetch first iteration's weights

    for (int dy = 0; dy < 3; ++dy) {
        asm volatile("s_waitcnt vmcnt(0)" ::: "memory");  // stage of this buf done
        __syncthreads();
        const char* lb = smem[dy & 1];

#pragma unroll
        for (int cc = 0; cc < 6; ++cc) {
            s16x8 (&cur)[3][3] = (cc & 1) ? afB : afA;    // compile-time select
            s16x8 (&nxt)[3][3] = (cc & 1) ? afA : afB;

            if (cc == 5) {
                __builtin_amdgcn_sched_barrier(0);
                if (dy < 2) {
                    stage((char*)smem[(dy + 1) & 1], y + dy + 1);
                    loadAF(nxt, dy + 1, 0);   // cross-barrier af prefetch
                }
                __builtin_amdgcn_sched_barrier(0);
            } else {
                loadAF(nxt, dy, cc + 1);      // prefetch next cc's weights
            }

            s16x8 bv[3][3];
#pragma unroll
            for (int j2 = 0; j2 < 3; ++j2)
#pragma unroll
                for (int dx = 0; dx < 3; ++dx) {
                    const int q = j2 * 16 + ln15 + dx;
                    bv[j2][dx] = *(const s16x8*)(lb + q * 384 +
                                    ((cc * 64 + kg * 16) ^ ((q & 7) << 4)));
                }
#pragma unroll
            for (int i = 0; i < 3; ++i)
#pragma unroll
                for (int j2 = 0; j2 < 3; ++j2)
#pragma unroll
                    for (int dx = 0; dx < 3; ++dx)
                        acc[i][j2] = __builtin_amdgcn_mfma_f32_16x16x32_bf16(
                            cur[dx][i], bv[j2][dx], acc[i][j2], 0, 0, 0);
        }
    }

    // phase layout: dst[((b*9 + (y%3)*3 + s%3)*192 + co)*1024 + (y/3)*32 + s/3]
    unsigned short* yb = (unsigned short*)yout;
    const int ph = y % 3, lh = y / 3;
    int poff[3];
#pragma unroll
    for (int j2 = 0; j2 < 3; ++j2) {
        const int s  = sx * 48 + j2 * 16 + ln15;
        const int pw = s % 3, lw = s / 3;
        poff[j2] = ((b * FK + ph * 3 + pw) * C) * L + lh * 32 + lw;
    }
#pragma unroll
    for (int i = 0; i < 3; ++i)
#pragma unroll
        for (int rr = 0; rr < 4; ++rr) {
            const int co = wc * 48 + i * 16 + kg * 4 + rr;
#pragma unroll
            for (int j2 = 0; j2 < 3; ++j2)
                yb[(size_t)poff[j2] + co * L] = f2b(acc[i][j2][rr]);
        }
}

// ---------------------------------------------------------------------------
// FINAL conv (R10 wide-s structure, no spill, VGPR 88): wave = 48co x 96s x 1y,
// per-batch normW weights. XCD-batch affinity: b = id&7 -> each XCD runs one
// batch (663KB normW + streamed xpad rows stay in its own L2).
// ---------------------------------------------------------------------------
__global__ __launch_bounds__(256)
void conv_final(const unsigned short* __restrict__ xpadT,
                const unsigned short* __restrict__ wA,
                float* __restrict__ yout) {
    __shared__ __align__(16) char smem[HP * 384];   // 37632 B
    const int tid  = threadIdx.x;
    const int b    = blockIdx.x & 7;    // XCD id on 8-XCD dispatch
    const int y    = blockIdx.x >> 3;
    const int lane = tid & 63, wc = tid >> 6;
    const int ln15 = lane & 15, kg = lane >> 4;

    const unsigned short* wp = wA + (size_t)b * WELEM;

    int gofs[9];
#pragma unroll
    for (int it = 0; it < 9; ++it) {
        const int m = it * 256 + tid;
        const int q = m / 24, c16 = m - q * 24;
        gofs[it] = q * 384 + ((c16 * 16) ^ ((q & 7) << 4));
    }
    int gtail = 0;
    if (tid < 48) {
        const int m = 2304 + tid;
        const int q = m / 24, c16 = m - q * 24;
        gtail = q * 384 + ((c16 * 16) ^ ((q & 7) << 4));
    }

    auto stage = [&](int prow) {
        const char* rb = (const char*)(xpadT + ((size_t)(b * HP + prow)) * HP * 192);
#pragma unroll
        for (int it = 0; it < 9; ++it)
            __builtin_amdgcn_global_load_lds(
                (glb_u32p)(const void*)(rb + gofs[it]),
                (lds_u32p)(void*)(smem + it * 4096 + wc * 1024), 16, 0, 0);
        if (tid < 48)
            __builtin_amdgcn_global_load_lds(
                (glb_u32p)(const void*)(rb + gtail),
                (lds_u32p)(void*)(smem + 36864 + wc * 1024), 16, 0, 0);
    };

    f32x4 acc[3][6];
#pragma unroll
    for (int i = 0; i < 3; ++i)
#pragma unroll
        for (int j = 0; j < 6; ++j)
            acc[i][j] = (f32x4){0.f, 0.f, 0.f, 0.f};

    stage(y);

#pragma unroll 1
    for (int dy = 0; dy < 3; ++dy) {
        asm volatile("s_waitcnt vmcnt(0)" ::: "memory");
        __syncthreads();

#pragma unroll 1
        for (int cc = 0; cc < 6; ++cc) {
#pragma unroll
            for (int dx = 0; dx < 3; ++dx) {
                const int cid = (((3 * dy + dx) * 12 + wc * 3) * 6 + cc);
                const s16x8 af0 = *(const s16x8*)(wp + (size_t)cid * 512 + lane * 8);
                const s16x8 af1 = *(const s16x8*)(wp + (size_t)(cid + 6) * 512 + lane * 8);
                const s16x8 af2 = *(const s16x8*)(wp + (size_t)(cid + 12) * 512 + lane * 8);
#pragma unroll
                for (int j = 0; j < 6; ++j) {
                    const int q = j * 16 + ln15 + dx;
                    const s16x8 bv = *(const s16x8*)(smem + q * 384 +
                                        ((cc * 64 + kg * 16) ^ ((q & 7) << 4)));
                    acc[0][j] = __builtin_amdgcn_mfma_f32_16x16x32_bf16(af0, bv, acc[0][j], 0, 0, 0);
                    acc[1][j] = __builtin_amdgcn_mfma_f32_16x16x32_bf16(af1, bv, acc[1][j], 0, 0, 0);
                    acc[2][j] = __builtin_amdgcn_mfma_f32_16x16x32_bf16(af2, bv, acc[2][j], 0, 0, 0);
                }
            }
        }
        if (dy < 2) {
            __syncthreads();          // all waves done reading smem
            stage(y + dy + 1);
        }
    }

#pragma unroll
    for (int i = 0; i < 3; ++i)
#pragma unroll
        for (int rr = 0; rr < 4; ++rr) {
            const int co = wc * 48 + i * 16 + kg * 4 + rr;
            const size_t base = (((size_t)b * C + co) * H + y) * W;
#pragma unroll
            for (int j = 0; j < 6; ++j)
                yout[base + j * 16 + ln15] = acc[i][j][rr];
        }
}

// ---------------------------------------------------------------------------
// attn MFMA with XCD-batch affinity: 1-D grid 288; b = id&7 -> each XCD owns
// one batch; the 4 (of,cf) quarters of each (b,p) are temporally adjacent.
// Block = 96c x 96o quarter, 4 waves 48x48, BK=64 double-buffered staging.
// Epilogue: attnT[b][p][o][c] f32 + fused f64 sum/ssq partials.
// ---------------------------------------------------------------------------
__global__ __launch_bounds__(256, 3)
void attn_mfma(const unsigned short* __restrict__ kcS,
               const unsigned short* __restrict__ qcS,
               float* __restrict__ attnT,
               double* __restrict__ part) {
    __shared__ __align__(16) char smem[2][24576];   // [buf][A 12KB | B 12KB]
    const int tid  = threadIdx.x;
    const int lane = tid & 63, wid = tid >> 6;
    const int wq   = wid & 1, wp = wid >> 1;
    const int ln15 = lane & 15, kg = lane >> 4;
    const int id   = blockIdx.x;        // 0..287
    const int b    = id & 7;            // XCD id
    const int j5   = id >> 3;           // 0..35
    const int quarter = j5 & 3;
    const int p    = j5 >> 2;           // 0..8
    const int of   = quarter & 1, cf = quarter >> 1;

    const char* Abase = (const char*)(kcS + ((size_t)(b * FK + p) * C + cf * 96) * L);
    const char* Bbase = (const char*)(qcS + ((size_t)(b * FK + p) * C + of * 96) * L);

    int gofs[3];
#pragma unroll
    for (int it = 0; it < 3; ++it) {
        const int chunk = it * 256 + tid;
        const int row = chunk >> 3, c16 = chunk & 7;
        gofs[it] = row * 2048 + ((c16 * 16) ^ ((row & 7) << 4));
    }

    auto stage = [&](int bufi, int t) {
        const char* Ab = Abase + t * 128;
        const char* Bb = Bbase + t * 128;
        char* lb = (char*)smem[bufi];
#pragma unroll
        for (int it = 0; it < 3; ++it)
            __builtin_amdgcn_global_load_lds(
                (glb_u32p)(const void*)(Ab + gofs[it]),
                (lds_u32p)(void*)(lb + it * 4096 + wid * 1024), 16, 0, 0);
#pragma unroll
        for (int it = 0; it < 3; ++it)
            __builtin_amdgcn_global_load_lds(
                (glb_u32p)(const void*)(Bb + gofs[it]),
                (lds_u32p)(void*)(lb + 12288 + it * 4096 + wid * 1024), 16, 0, 0);
    };

    f32x4 acc[3][3];
#pragma unroll
    for (int i = 0; i < 3; ++i)
#pragma unroll
        for (int j = 0; j < 3; ++j)
            acc[i][j] = (f32x4){0.f, 0.f, 0.f, 0.f};

    stage(0, 0);
    asm volatile("s_waitcnt vmcnt(0)" ::: "memory");
    __syncthreads();

    for (int t = 0; t < 16; ++t) {
        if (t < 15) stage((t + 1) & 1, t + 1);
        const char* lb = (const char*)smem[t & 1];
#pragma unroll
        for (int ks = 0; ks < 2; ++ks) {
            s16x8 af[3], bf[3];
#pragma unroll
            for (int i = 0; i < 3; ++i) {
                const int row = wp * 48 + i * 16 + ln15;
                af[i] = *(const s16x8*)(lb + row * 128 +
                                        ((ks * 64 + kg * 16) ^ ((row & 7) << 4)));
            }
#pragma unroll
            for (int j = 0; j < 3; ++j) {
                const int row = wq * 48 + j * 16 + ln15;
                bf[j] = *(const s16x8*)(lb + 12288 + row * 128 +
                                        ((ks * 64 + kg * 16) ^ ((row & 7) << 4)));
            }
#pragma unroll
            for (int i = 0; i < 3; ++i)
#pragma unroll
                for (int j = 0; j < 3; ++j)
                    acc[i][j] = __builtin_amdgcn_mfma_f32_16x16x32_bf16(
                        af[i], bf[j], acc[i][j], 0, 0, 0);
        }
        if (t < 15) {
            asm volatile("s_waitcnt vmcnt(0)" ::: "memory");
            __syncthreads();
        }
    }

    __syncthreads();
    double s = 0.0, ss = 0.0;
#pragma unroll
    for (int i = 0; i < 3; ++i)
#pragma unroll
        for (int j = 0; j < 3; ++j)
#pragma unroll
            for (int r = 0; r < 4; ++r) {
                const double v = (double)acc[i][j][r];
                s += v; ss += v * v;
            }
    double* ls  = (double*)&smem[0][0];
    double* lss = ls + 256;
    ls[tid] = s; lss[tid] = ss;
    __syncthreads();
    for (int st = 128; st; st >>= 1) {
        if (tid < st) { ls[tid] += ls[tid + st]; lss[tid] += lss[tid + st]; }
        __syncthreads();
    }
    if (tid == 0) {
        const int bf_ = ((b * FK + p) << 2) + quarter;
        part[2 * bf_]     = ls[0];
        part[2 * bf_ + 1] = lss[0];
    }

    float* ap = attnT + (size_t)(b * FK + p) * C * C;
#pragma unroll
    for (int i = 0; i < 3; ++i) {
        const int c0 = cf * 96 + wp * 48 + i * 16 + kg * 4;
#pragma unroll
        for (int j = 0; j < 3; ++j) {
            const int o = of * 96 + wq * 48 + j * 16 + ln15;
            *(f32x4*)(ap + o * C + c0) = acc[i][j];
        }
    }
}

// ---------------------------------------------------------------------------
// normW packed + INLINE finalize: every block redundantly reduces the 288
// f64 partial pairs (4.6KB, L2-hot, deterministic) -> alpha/beta, then
// out[b][chunk][lane][t] = bf16(alpha*attnT[b][p][co][ci]+beta).
// ---------------------------------------------------------------------------
__global__ __launch_bounds__(256) void norm_w(const float* __restrict__ attnT,
                                              const double* __restrict__ part,
                                              const float* __restrict__ momp,
                                              unsigned short* __restrict__ o) {
    __shared__ double ls[256], lss[256];
    __shared__ float sAB[2];
    const int tid = threadIdx.x;
    double s = 0.0, ss = 0.0;
    for (int i = tid; i < 288; i += 256) {
        s += part[2 * i]; ss += part[2 * i + 1];
    }
    ls[tid] = s; lss[tid] = ss;
    __syncthreads();
    for (int st = 128; st; st >>= 1) {
        if (tid < st) { ls[tid] += ls[tid + st]; lss[tid] += lss[tid + st]; }
        __syncthreads();
    }
    if (tid == 0) {
        const double n    = (double)(B * FK * C * C);
        const double mean = ls[0] / n;
        double var        = (lss[0] - ls[0] * ls[0] / n) / (n - 1.0);
        if (var < 0.0) var = 0.0;
        const double scale = 1.0 / (sqrt(var) + 1e-4);
        sAB[0] = (float)((double)momp[0] + scale);  // alpha
        sAB[1] = (float)(-mean * scale);            // beta
    }
    __syncthreads();
    const float alpha = sAB[0], beta = sAB[1];

    const int g = (blockIdx.x * 256 + tid) * 4;
    const int chunk = g >> 9, within = g & 511;
    const int lane = within >> 3, t0 = within & 7;
    const int cc = chunk % 6, c2 = chunk / 6;
    const int cot = c2 % 12, pb = c2 / 12;
    const int p = pb % FK, b = pb / FK;
    const int co = cot * 16 + (lane & 15);
    const int ci = cc * 32 + (lane >> 4) * 8 + t0;
    const float4 v = *(const float4*)(attnT + (((size_t)(b * FK + p) * C + co) * C + ci));
    s16x4 r;
    r[0] = (short)f2b(fmaf(alpha, v.x, beta));
    r[1] = (short)f2b(fmaf(alpha, v.y, beta));
    r[2] = (short)f2b(fmaf(alpha, v.z, beta));
    r[3] = (short)f2b(fmaf(alpha, v.w, beta));
    *(s16x4*)(o + g) = r;
}

} // anonymous namespace

extern "C" void kernel_launch(void* const* d_in, const int* in_sizes, int n_in,
                              void* d_out, int out_size, void* d_ws, size_t ws_size,
                              hipStream_t stream) {
    (void)in_sizes; (void)n_in; (void)out_size; (void)ws_size;
    const float* x1   = (const float*)d_in[0];
    const float* x2   = (const float*)d_in[1];
    const float* kw   = (const float*)d_in[2];
    const float* qw   = (const float*)d_in[3];
    const float* momp = (const float*)d_in[4];

    char* ws = (char*)d_ws;
    unsigned short* xpad1 = (unsigned short*)ws;                   // 29,503,488
    unsigned short* xpad2 = (unsigned short*)(ws + 29503488);      // 29,503,488
    unsigned short* kwA   = (unsigned short*)(ws + 59006976);      //    663,552
    unsigned short* qwA   = (unsigned short*)(ws + 59670528);      //    663,552
    unsigned short* kcS   = (unsigned short*)(ws + 60334080);      // 28,311,552
    float*          attnT = (float*)(ws + 88645632);               // 10,616,832
    double*         part  = (double*)(ws + 99262464);              //      4,608
    unsigned short* normW = kcS;            // kcS dead after attn; 5,308,416 B
    unsigned short* qcS   = (unsigned short*)d_out;  // scratch until final conv

    // merged prep: prep_x (4608) + prep_w (2592) + border_zero (582)
    prep_all<<<7782, 256, 0, stream>>>(x1, x2, kw, qw, xpad1, kwA, qwA);

    // both front convs in ONE dispatch, XCD-affinity mapped, af reg-prefetch
    conv_front<<<3072, 256, 0, stream>>>(xpad1, xpad2, kwA, qwA, kcS, qcS);

    attn_mfma<<<288, 256, 0, stream>>>(kcS, qcS, attnT, part);

    norm_w<<<2592, 256, 0, stream>>>(attnT, part, momp, normW);

    conv_final<<<768, 256, 0, stream>>>(xpad1, normW, (float*)d_out);
}

// Round 18
// 230.655 us; speedup vs baseline: 1.4614x; 1.4614x over previous
//
#include <hip/hip_runtime.h>
#include <math.h>

typedef __attribute__((ext_vector_type(8))) short s16x8;
typedef __attribute__((ext_vector_type(4))) short s16x4;
typedef __attribute__((ext_vector_type(4))) float f32x4;

typedef unsigned int u32;
typedef __attribute__((address_space(3))) u32* lds_u32p;
typedef const __attribute__((address_space(1))) u32* glb_u32p;

namespace {

constexpr int B  = 8;
constexpr int C  = 192;
constexpr int H  = 96;
constexpr int W  = 96;
constexpr int FK = 9;
constexpr int HP = 98;    // padded
constexpr int L  = 1024;  // 32x32 patch grid per phase
constexpr int WCHUNK = FK * 12 * 6;          // 648 packed 1KB chunks per tensor
constexpr int WELEM  = WCHUNK * 512;         // 331776 bf16 elements
constexpr size_t XPAD_ELEMS = (size_t)B * HP * HP * 192;

__device__ inline unsigned short f2b(float f) {
    unsigned int x = __float_as_uint(f);
    x += 0x7fffu + ((x >> 16) & 1u);
    return (unsigned short)(x >> 16);
}

// ---------------------------------------------------------------------------
// MERGED prep: [0,4608) prep_x (x->xpadT bf16 channel-last, both tensors),
// [4608,7200) prep_w (fragment-linear weight pack, both tensors),
// [7200,7782) border_zero (zero pad borders of both xpad tensors).
// ---------------------------------------------------------------------------
__global__ __launch_bounds__(256) void prep_all(const float* __restrict__ x1,
                                                const float* __restrict__ x2,
                                                const float* __restrict__ kw,
                                                const float* __restrict__ qw,
                                                unsigned short* __restrict__ xpadT,
                                                unsigned short* __restrict__ kwA,
                                                unsigned short* __restrict__ qwA) {
    __shared__ float xs[192][33];
    const int gid = blockIdx.x;
    const int tid = threadIdx.x;

    if (gid < 4608) {
        const int bx = gid % 3, by = (gid / 3) % 96, bz = gid / 288;
        const int x0 = bx * 32, y = by;
        const int b = bz & 7, t = bz >> 3;
        const float* x = t ? x2 : x1;
        unsigned short* dst = xpadT + (size_t)t * XPAD_ELEMS;
        for (int e = tid; e < 192 * 32; e += 256) {
            const int ci = e >> 5, xx = e & 31;
            xs[ci][xx] = x[(((size_t)b * C + ci) * H + y) * W + x0 + xx];
        }
        __syncthreads();
        for (int e = tid; e < 32 * 192; e += 256) {
            const int pos = e / 192, ci = e - pos * 192;
            dst[(((size_t)(b * HP + y + 1)) * HP + x0 + pos + 1) * 192 + ci] =
                f2b(xs[ci][pos]);
        }
    } else if (gid < 7200) {
        int idx = (gid - 4608) * 256 + tid;
        const float* src = kw;
        unsigned short* dst = kwA;
        if (idx >= WELEM) { idx -= WELEM; src = qw; dst = qwA; }
        const int chunk = idx >> 9, within = idx & 511;
        const int lane = within >> 3, t = within & 7;
        const int kg = lane >> 4, r15 = lane & 15;
        const int cc = chunk % 6, c2 = chunk / 6;
        const int cot = c2 % 12, p = c2 / 12;
        const int co = cot * 16 + r15;
        const int ci = cc * 32 + kg * 8 + t;
        dst[idx] = f2b(src[((size_t)co * C + ci) * FK + p]);
    } else {
        const int c   = (gid - 7200) * 256 + tid;
        const int c16 = c % 24;
        const int p_  = c / 24;
        const int pos = p_ % 388;
        const int bt  = p_ / 388;      // 0..15 spans xpad1 then xpad2
        int yy, xx;
        if (pos < 98)       { yy = 0;          xx = pos; }
        else if (pos < 196) { yy = 97;         xx = pos - 98; }
        else if (pos < 292) { yy = pos - 195;  xx = 0; }
        else                { yy = pos - 291;  xx = 97; }
        const size_t off = (((size_t)bt * HP + yy) * HP + xx) * 192 + c16 * 8;
        *(s16x8*)(xpadT + off) = (s16x8){0, 0, 0, 0, 0, 0, 0, 0};
    }
}

// ---------------------------------------------------------------------------
// FRONT conv (R14/R16 optimum: 137us merged, VGPR 84, FETCH 41MB, no spill).
// R8 inner structure: 4 waves 48co x 48s x 1y; 2 x 19.2KB LDS dbuf;
// stage(dy+1) issued at cc==5 pinned by sched_barriers; batched 9-af.
// XCD-affinity map: id&7 = XCD; each XCD owns 2 (tensor,b) pairs; y ascends
// with sx siblings adjacent -> overlapping row windows hit the SAME L2
// (measured FETCH 101->41MB). Five structural alternatives all failed:
// R9/R11 acc-widening spilled, R10 wide-s null, R15 barrier-free lost
// occupancy, R17 af-reg-dbuf spilled via reference-select (WRITE 425MB).
// This is the converged HIP-source optimum for this kernel family.
// ---------------------------------------------------------------------------
__global__ __launch_bounds__(256, 3)
void conv_front(const unsigned short* __restrict__ xpadA,
                const unsigned short* __restrict__ xpadB,
                const unsigned short* __restrict__ wA,
                const unsigned short* __restrict__ wB,
                void* __restrict__ youtA,
                void* __restrict__ youtB) {
    __shared__ __align__(16) char smem[2][19200];
    const int tid  = threadIdx.x;
    const int id   = blockIdx.x;            // 0..3071
    const int xcd  = id & 7;
    const int j    = id >> 3;               // 0..383
    const int pair = j / 192;               // 0..1
    const int k    = j - pair * 192;
    const int sx   = k & 1;
    const int y    = k >> 1;                // 0..95
    const int bt   = xcd * 2 + pair;        // 0..15
    const int b    = bt & 7;
    const int t    = bt >> 3;
    const unsigned short* xpadT = t ? xpadB : xpadA;
    const unsigned short* wp    = t ? wB : wA;
    void* yout = t ? youtB : youtA;
    const int lane = tid & 63, wc = tid >> 6;
    const int ln15 = lane & 15, kg = lane >> 4;

    // staging: 50 pos x 24 chunks(16B) = 1200 chunks; 4 rounds + 176 tail
    int gfull[4];
#pragma unroll
    for (int it = 0; it < 4; ++it) {
        const int m = it * 256 + tid;
        const int q = m / 24, c16 = m - q * 24;
        gfull[it] = (sx * 48 + q) * 384 + ((c16 * 16) ^ ((q & 7) << 4));
    }
    int gtail = 0;
    if (tid < 176) {
        const int m = 1024 + tid;
        const int q = m / 24, c16 = m - q * 24;
        gtail = (sx * 48 + q) * 384 + ((c16 * 16) ^ ((q & 7) << 4));
    }

    auto stage = [&](char* lb, int prow) {
        const char* rowbase = (const char*)(xpadT + ((size_t)(b * HP + prow)) * HP * 192);
#pragma unroll
        for (int it = 0; it < 4; ++it)
            __builtin_amdgcn_global_load_lds(
                (glb_u32p)(const void*)(rowbase + gfull[it]),
                (lds_u32p)(void*)(lb + it * 4096 + wc * 1024), 16, 0, 0);
        if (tid < 176)
            __builtin_amdgcn_global_load_lds(
                (glb_u32p)(const void*)(rowbase + gtail),
                (lds_u32p)(void*)(lb + 16384 + wc * 1024), 16, 0, 0);
    };

    f32x4 acc[3][3];
#pragma unroll
    for (int i = 0; i < 3; ++i)
#pragma unroll
        for (int j2 = 0; j2 < 3; ++j2)
            acc[i][j2] = (f32x4){0.f, 0.f, 0.f, 0.f};

    stage(smem[0], y);

    for (int dy = 0; dy < 3; ++dy) {
        asm volatile("s_waitcnt vmcnt(0)" ::: "memory");  // stage of this buf done
        __syncthreads();
        const char* lb = smem[dy & 1];

#pragma unroll
        for (int cc = 0; cc < 6; ++cc) {
            s16x8 af[3][3];
#pragma unroll
            for (int dx = 0; dx < 3; ++dx)
#pragma unroll
                for (int i = 0; i < 3; ++i) {
                    const int chunkid = ((3 * dy + dx) * 12 + wc * 3 + i) * 6 + cc;
                    af[dx][i] = *(const s16x8*)(wp + (size_t)chunkid * 512 + lane * 8);
                }
            if (cc == 5) {
                __builtin_amdgcn_sched_barrier(0);   // af issues stay above
                if (dy < 2) stage((char*)smem[(dy + 1) & 1], y + dy + 1);
                __builtin_amdgcn_sched_barrier(0);   // stage issue pinned here
            }
            s16x8 bv[3][3];
#pragma unroll
            for (int j2 = 0; j2 < 3; ++j2)
#pragma unroll
                for (int dx = 0; dx < 3; ++dx) {
                    const int q = j2 * 16 + ln15 + dx;
                    bv[j2][dx] = *(const s16x8*)(lb + q * 384 +
                                    ((cc * 64 + kg * 16) ^ ((q & 7) << 4)));
                }
#pragma unroll
            for (int i = 0; i < 3; ++i)
#pragma unroll
                for (int j2 = 0; j2 < 3; ++j2)
#pragma unroll
                    for (int dx = 0; dx < 3; ++dx)
                        acc[i][j2] = __builtin_amdgcn_mfma_f32_16x16x32_bf16(
                            af[dx][i], bv[j2][dx], acc[i][j2], 0, 0, 0);
        }
    }

    // phase layout: dst[((b*9 + (y%3)*3 + s%3)*192 + co)*1024 + (y/3)*32 + s/3]
    unsigned short* yb = (unsigned short*)yout;
    const int ph = y % 3, lh = y / 3;
    int poff[3];
#pragma unroll
    for (int j2 = 0; j2 < 3; ++j2) {
        const int s  = sx * 48 + j2 * 16 + ln15;
        const int pw = s % 3, lw = s / 3;
        poff[j2] = ((b * FK + ph * 3 + pw) * C) * L + lh * 32 + lw;
    }
#pragma unroll
    for (int i = 0; i < 3; ++i)
#pragma unroll
        for (int rr = 0; rr < 4; ++rr) {
            const int co = wc * 48 + i * 16 + kg * 4 + rr;
#pragma unroll
            for (int j2 = 0; j2 < 3; ++j2)
                yb[(size_t)poff[j2] + co * L] = f2b(acc[i][j2][rr]);
        }
}

// ---------------------------------------------------------------------------
// FINAL conv (R10 wide-s structure, no spill, VGPR 88): wave = 48co x 96s x 1y,
// per-batch normW weights. XCD-batch affinity: b = id&7 -> each XCD runs one
// batch (663KB normW + streamed xpad rows stay in its own L2).
// ---------------------------------------------------------------------------
__global__ __launch_bounds__(256)
void conv_final(const unsigned short* __restrict__ xpadT,
                const unsigned short* __restrict__ wA,
                float* __restrict__ yout) {
    __shared__ __align__(16) char smem[HP * 384];   // 37632 B
    const int tid  = threadIdx.x;
    const int b    = blockIdx.x & 7;    // XCD id on 8-XCD dispatch
    const int y    = blockIdx.x >> 3;
    const int lane = tid & 63, wc = tid >> 6;
    const int ln15 = lane & 15, kg = lane >> 4;

    const unsigned short* wp = wA + (size_t)b * WELEM;

    int gofs[9];
#pragma unroll
    for (int it = 0; it < 9; ++it) {
        const int m = it * 256 + tid;
        const int q = m / 24, c16 = m - q * 24;
        gofs[it] = q * 384 + ((c16 * 16) ^ ((q & 7) << 4));
    }
    int gtail = 0;
    if (tid < 48) {
        const int m = 2304 + tid;
        const int q = m / 24, c16 = m - q * 24;
        gtail = q * 384 + ((c16 * 16) ^ ((q & 7) << 4));
    }

    auto stage = [&](int prow) {
        const char* rb = (const char*)(xpadT + ((size_t)(b * HP + prow)) * HP * 192);
#pragma unroll
        for (int it = 0; it < 9; ++it)
            __builtin_amdgcn_global_load_lds(
                (glb_u32p)(const void*)(rb + gofs[it]),
                (lds_u32p)(void*)(smem + it * 4096 + wc * 1024), 16, 0, 0);
        if (tid < 48)
            __builtin_amdgcn_global_load_lds(
                (glb_u32p)(const void*)(rb + gtail),
                (lds_u32p)(void*)(smem + 36864 + wc * 1024), 16, 0, 0);
    };

    f32x4 acc[3][6];
#pragma unroll
    for (int i = 0; i < 3; ++i)
#pragma unroll
        for (int j = 0; j < 6; ++j)
            acc[i][j] = (f32x4){0.f, 0.f, 0.f, 0.f};

    stage(y);

#pragma unroll 1
    for (int dy = 0; dy < 3; ++dy) {
        asm volatile("s_waitcnt vmcnt(0)" ::: "memory");
        __syncthreads();

#pragma unroll 1
        for (int cc = 0; cc < 6; ++cc) {
#pragma unroll
            for (int dx = 0; dx < 3; ++dx) {
                const int cid = (((3 * dy + dx) * 12 + wc * 3) * 6 + cc);
                const s16x8 af0 = *(const s16x8*)(wp + (size_t)cid * 512 + lane * 8);
                const s16x8 af1 = *(const s16x8*)(wp + (size_t)(cid + 6) * 512 + lane * 8);
                const s16x8 af2 = *(const s16x8*)(wp + (size_t)(cid + 12) * 512 + lane * 8);
#pragma unroll
                for (int j = 0; j < 6; ++j) {
                    const int q = j * 16 + ln15 + dx;
                    const s16x8 bv = *(const s16x8*)(smem + q * 384 +
                                        ((cc * 64 + kg * 16) ^ ((q & 7) << 4)));
                    acc[0][j] = __builtin_amdgcn_mfma_f32_16x16x32_bf16(af0, bv, acc[0][j], 0, 0, 0);
                    acc[1][j] = __builtin_amdgcn_mfma_f32_16x16x32_bf16(af1, bv, acc[1][j], 0, 0, 0);
                    acc[2][j] = __builtin_amdgcn_mfma_f32_16x16x32_bf16(af2, bv, acc[2][j], 0, 0, 0);
                }
            }
        }
        if (dy < 2) {
            __syncthreads();          // all waves done reading smem
            stage(y + dy + 1);
        }
    }

#pragma unroll
    for (int i = 0; i < 3; ++i)
#pragma unroll
        for (int rr = 0; rr < 4; ++rr) {
            const int co = wc * 48 + i * 16 + kg * 4 + rr;
            const size_t base = (((size_t)b * C + co) * H + y) * W;
#pragma unroll
            for (int j = 0; j < 6; ++j)
                yout[base + j * 16 + ln15] = acc[i][j][rr];
        }
}

// ---------------------------------------------------------------------------
// attn MFMA with XCD-batch affinity: 1-D grid 288; b = id&7 -> each XCD owns
// one batch; the 4 (of,cf) quarters of each (b,p) are temporally adjacent.
// Block = 96c x 96o quarter, 4 waves 48x48, BK=64 double-buffered staging.
// Epilogue: attnT[b][p][o][c] f32 + fused f64 sum/ssq partials.
// ---------------------------------------------------------------------------
__global__ __launch_bounds__(256, 3)
void attn_mfma(const unsigned short* __restrict__ kcS,
               const unsigned short* __restrict__ qcS,
               float* __restrict__ attnT,
               double* __restrict__ part) {
    __shared__ __align__(16) char smem[2][24576];   // [buf][A 12KB | B 12KB]
    const int tid  = threadIdx.x;
    const int lane = tid & 63, wid = tid >> 6;
    const int wq   = wid & 1, wp = wid >> 1;
    const int ln15 = lane & 15, kg = lane >> 4;
    const int id   = blockIdx.x;        // 0..287
    const int b    = id & 7;            // XCD id
    const int j5   = id >> 3;           // 0..35
    const int quarter = j5 & 3;
    const int p    = j5 >> 2;           // 0..8
    const int of   = quarter & 1, cf = quarter >> 1;

    const char* Abase = (const char*)(kcS + ((size_t)(b * FK + p) * C + cf * 96) * L);
    const char* Bbase = (const char*)(qcS + ((size_t)(b * FK + p) * C + of * 96) * L);

    int gofs[3];
#pragma unroll
    for (int it = 0; it < 3; ++it) {
        const int chunk = it * 256 + tid;
        const int row = chunk >> 3, c16 = chunk & 7;
        gofs[it] = row * 2048 + ((c16 * 16) ^ ((row & 7) << 4));
    }

    auto stage = [&](int bufi, int t) {
        const char* Ab = Abase + t * 128;
        const char* Bb = Bbase + t * 128;
        char* lb = (char*)smem[bufi];
#pragma unroll
        for (int it = 0; it < 3; ++it)
            __builtin_amdgcn_global_load_lds(
                (glb_u32p)(const void*)(Ab + gofs[it]),
                (lds_u32p)(void*)(lb + it * 4096 + wid * 1024), 16, 0, 0);
#pragma unroll
        for (int it = 0; it < 3; ++it)
            __builtin_amdgcn_global_load_lds(
                (glb_u32p)(const void*)(Bb + gofs[it]),
                (lds_u32p)(void*)(lb + 12288 + it * 4096 + wid * 1024), 16, 0, 0);
    };

    f32x4 acc[3][3];
#pragma unroll
    for (int i = 0; i < 3; ++i)
#pragma unroll
        for (int j = 0; j < 3; ++j)
            acc[i][j] = (f32x4){0.f, 0.f, 0.f, 0.f};

    stage(0, 0);
    asm volatile("s_waitcnt vmcnt(0)" ::: "memory");
    __syncthreads();

    for (int t = 0; t < 16; ++t) {
        if (t < 15) stage((t + 1) & 1, t + 1);
        const char* lb = (const char*)smem[t & 1];
#pragma unroll
        for (int ks = 0; ks < 2; ++ks) {
            s16x8 af[3], bf[3];
#pragma unroll
            for (int i = 0; i < 3; ++i) {
                const int row = wp * 48 + i * 16 + ln15;
                af[i] = *(const s16x8*)(lb + row * 128 +
                                        ((ks * 64 + kg * 16) ^ ((row & 7) << 4)));
            }
#pragma unroll
            for (int j = 0; j < 3; ++j) {
                const int row = wq * 48 + j * 16 + ln15;
                bf[j] = *(const s16x8*)(lb + 12288 + row * 128 +
                                        ((ks * 64 + kg * 16) ^ ((row & 7) << 4)));
            }
#pragma unroll
            for (int i = 0; i < 3; ++i)
#pragma unroll
                for (int j = 0; j < 3; ++j)
                    acc[i][j] = __builtin_amdgcn_mfma_f32_16x16x32_bf16(
                        af[i], bf[j], acc[i][j], 0, 0, 0);
        }
        if (t < 15) {
            asm volatile("s_waitcnt vmcnt(0)" ::: "memory");
            __syncthreads();
        }
    }

    __syncthreads();
    double s = 0.0, ss = 0.0;
#pragma unroll
    for (int i = 0; i < 3; ++i)
#pragma unroll
        for (int j = 0; j < 3; ++j)
#pragma unroll
            for (int r = 0; r < 4; ++r) {
                const double v = (double)acc[i][j][r];
                s += v; ss += v * v;
            }
    double* ls  = (double*)&smem[0][0];
    double* lss = ls + 256;
    ls[tid] = s; lss[tid] = ss;
    __syncthreads();
    for (int st = 128; st; st >>= 1) {
        if (tid < st) { ls[tid] += ls[tid + st]; lss[tid] += lss[tid + st]; }
        __syncthreads();
    }
    if (tid == 0) {
        const int bf_ = ((b * FK + p) << 2) + quarter;
        part[2 * bf_]     = ls[0];
        part[2 * bf_ + 1] = lss[0];
    }

    float* ap = attnT + (size_t)(b * FK + p) * C * C;
#pragma unroll
    for (int i = 0; i < 3; ++i) {
        const int c0 = cf * 96 + wp * 48 + i * 16 + kg * 4;
#pragma unroll
        for (int j = 0; j < 3; ++j) {
            const int o = of * 96 + wq * 48 + j * 16 + ln15;
            *(f32x4*)(ap + o * C + c0) = acc[i][j];
        }
    }
}

// ---------------------------------------------------------------------------
// normW packed + INLINE finalize: every block redundantly reduces the 288
// f64 partial pairs (4.6KB, L2-hot, deterministic) -> alpha/beta, then
// out[b][chunk][lane][t] = bf16(alpha*attnT[b][p][co][ci]+beta).
// ---------------------------------------------------------------------------
__global__ __launch_bounds__(256) void norm_w(const float* __restrict__ attnT,
                                              const double* __restrict__ part,
                                              const float* __restrict__ momp,
                                              unsigned short* __restrict__ o) {
    __shared__ double ls[256], lss[256];
    __shared__ float sAB[2];
    const int tid = threadIdx.x;
    double s = 0.0, ss = 0.0;
    for (int i = tid; i < 288; i += 256) {
        s += part[2 * i]; ss += part[2 * i + 1];
    }
    ls[tid] = s; lss[tid] = ss;
    __syncthreads();
    for (int st = 128; st; st >>= 1) {
        if (tid < st) { ls[tid] += ls[tid + st]; lss[tid] += lss[tid + st]; }
        __syncthreads();
    }
    if (tid == 0) {
        const double n    = (double)(B * FK * C * C);
        const double mean = ls[0] / n;
        double var        = (lss[0] - ls[0] * ls[0] / n) / (n - 1.0);
        if (var < 0.0) var = 0.0;
        const double scale = 1.0 / (sqrt(var) + 1e-4);
        sAB[0] = (float)((double)momp[0] + scale);  // alpha
        sAB[1] = (float)(-mean * scale);            // beta
    }
    __syncthreads();
    const float alpha = sAB[0], beta = sAB[1];

    const int g = (blockIdx.x * 256 + tid) * 4;
    const int chunk = g >> 9, within = g & 511;
    const int lane = within >> 3, t0 = within & 7;
    const int cc = chunk % 6, c2 = chunk / 6;
    const int cot = c2 % 12, pb = c2 / 12;
    const int p = pb % FK, b = pb / FK;
    const int co = cot * 16 + (lane & 15);
    const int ci = cc * 32 + (lane >> 4) * 8 + t0;
    const float4 v = *(const float4*)(attnT + (((size_t)(b * FK + p) * C + co) * C + ci));
    s16x4 r;
    r[0] = (short)f2b(fmaf(alpha, v.x, beta));
    r[1] = (short)f2b(fmaf(alpha, v.y, beta));
    r[2] = (short)f2b(fmaf(alpha, v.z, beta));
    r[3] = (short)f2b(fmaf(alpha, v.w, beta));
    *(s16x4*)(o + g) = r;
}

} // anonymous namespace

extern "C" void kernel_launch(void* const* d_in, const int* in_sizes, int n_in,
                              void* d_out, int out_size, void* d_ws, size_t ws_size,
                              hipStream_t stream) {
    (void)in_sizes; (void)n_in; (void)out_size; (void)ws_size;
    const float* x1   = (const float*)d_in[0];
    const float* x2   = (const float*)d_in[1];
    const float* kw   = (const float*)d_in[2];
    const float* qw   = (const float*)d_in[3];
    const float* momp = (const float*)d_in[4];

    char* ws = (char*)d_ws;
    unsigned short* xpad1 = (unsigned short*)ws;                   // 29,503,488
    unsigned short* xpad2 = (unsigned short*)(ws + 29503488);      // 29,503,488
    unsigned short* kwA   = (unsigned short*)(ws + 59006976);      //    663,552
    unsigned short* qwA   = (unsigned short*)(ws + 59670528);      //    663,552
    unsigned short* kcS   = (unsigned short*)(ws + 60334080);      // 28,311,552
    float*          attnT = (float*)(ws + 88645632);               // 10,616,832
    double*         part  = (double*)(ws + 99262464);              //      4,608
    unsigned short* normW = kcS;            // kcS dead after attn; 5,308,416 B
    unsigned short* qcS   = (unsigned short*)d_out;  // scratch until final conv

    // merged prep: prep_x (4608) + prep_w (2592) + border_zero (582)
    prep_all<<<7782, 256, 0, stream>>>(x1, x2, kw, qw, xpad1, kwA, qwA);

    // both front convs in ONE dispatch, XCD-affinity mapped (converged optimum)
    conv_front<<<3072, 256, 0, stream>>>(xpad1, xpad2, kwA, qwA, kcS, qcS);

    attn_mfma<<<288, 256, 0, stream>>>(kcS, qcS, attnT, part);

    norm_w<<<2592, 256, 0, stream>>>(attnT, part, momp, normW);

    conv_final<<<768, 256, 0, stream>>>(xpad1, normW, (float*)d_out);
}